// Round 8
// baseline (139.813 us; speedup 1.0000x reference)
//
#include <hip/hip_runtime.h>

// Conv2D 3x3 stride-1 pad-1, C_IN=C_OUT=16, H=W=1024, fp32 in/out.
// Fused implicit-GEMM. v8: barrier-free single-wave blocks, byte-clean tiles.
//  - Evidence: every barrier-synced variant (r0-r3, r5, r7) sits at 39-52us
//    with all pipes <45% busy; fillBuffer (no barriers) does 6.5 TB/s on the
//    same chip. Per-CU budgets show no pipe saturated -> the loss is convoy
//    stall around block-wide barriers. r4 (barrier-free) failed only on
//    bytes (16-wide tile => 2.2x fetch) and 1-wave starvation; v8 fixes both.
//  - Block = 1 wave, 64x8 output tile, stages 10x66 halo'd rows. LDS
//    21120 B -> 7 blocks/CU; grid 16x128 = 2048 blocks. 7 self-paced
//    streams/CU, ZERO sync instructions; ordering = per-wave in-order DS
//    pipe + compiler waitcnts (pattern validated by r4 passing).
//  - Staging: 3 sweeps (rows -1..2, 3..6, 7..8), r1's proven coalesced
//    task map (lane = (row, 4px grp), 16 channel-strided float4 loads,
//    v_cvt_pk_bf16_f32 pack, XOR-swizzled ds_write). All vmcnt-waiting
//    packs are placed BEFORE any output stores are issued, so no wait can
//    degenerate to vmcnt(0)-with-64-stores-outstanding.
//  - Weights: r4's per-lane register gather from the hot 9KB filter
//    (L2-resident) -> a[5] v8s; no weight LDS, no table phase.
//  - LDS tile [slot 0..9][col 0..65][ch16], 32B/px, 16B-chunk XOR swizzle
//    phys = c ^ ((c>>3)&7) (r1-validated conflict behavior).
//  - Compute: 8 rows x 4 col-groups x 5 mfma_f32_16x16x32_bf16.

#define HH 1024
#define WW 1024
#define CIN 16
#define HWP (HH * WW)
#define TW 64
#define TH 8
#define LROWS 10               // slots: global rows h0-1 .. h0+8
#define LCOLS 66
#define NPIX (LROWS * LCOLS)   // 660 px * 32B = 21120 B

typedef short v8s __attribute__((ext_vector_type(8)));
typedef float v4f __attribute__((ext_vector_type(4)));
typedef unsigned int u32;

// packed {bf16(hi)<<16 | bf16(lo)}, hardware RNE
__device__ __forceinline__ u32 cvt_pk_bf16(float lo, float hi) {
    u32 r;
    asm("v_cvt_pk_bf16_f32 %0, %1, %2" : "=v"(r) : "v"(lo), "v"(hi));
    return r;
}

__device__ __forceinline__ int swz(int c) { return c ^ ((c >> 3) & 7); }

__global__ __launch_bounds__(64, 2)
void conv3x3_wave(const float* __restrict__ x,
                  const float* __restrict__ wgt,
                  const float* __restrict__ bias,
                  float* __restrict__ out) {
    __shared__ __align__(16) unsigned short sm[NPIX * 16];   // 21120 B

    const int lane = threadIdx.x;
    const int m = lane & 15;       // c_out row of A == pixel col of B/D
    const int q = lane >> 4;       // k-quad: supplies k = 8q..8q+7
    const int w0 = blockIdx.x * TW;
    const int h0 = blockIdx.y * TH;

    // ---- weight fragments in registers (gather from hot 9KB, L2-res) ----
    // a[g5] elem j = W[m][(t&1)*8+j][kh][kw], t = 4*g5+q, kh*3+kw = t>>1.
    v8s a[5];
    #pragma unroll
    for (int g5 = 0; g5 < 5; ++g5) {
        const int t = 4 * g5 + q;
        union { u32 u[4]; v8s v; } wv;
        if (t < 18) {
            const int base = m * 144 + (t & 1) * 72 + (t >> 1);
            #pragma unroll
            for (int jj = 0; jj < 4; ++jj) {
                const float lo = wgt[base + 18 * jj];      // j = 2jj
                const float hi = wgt[base + 18 * jj + 9];  // j = 2jj+1
                wv.u[jj] = cvt_pk_bf16(lo, hi);
            }
        } else {
            wv.u[0] = wv.u[1] = wv.u[2] = wv.u[3] = 0u;
        }
        a[g5] = wv.v;
    }
    float bl[4];
    #pragma unroll
    for (int i = 0; i < 4; ++i) bl[i] = bias[q * 4 + i];

    // ---- B-chunk offset bases: chunk t = 4g+q, t<=17 -> (kh,kw,half) ----
    int Kbase[5];
    #pragma unroll
    for (int g5 = 0; g5 < 5; ++g5) {
        int t = 4 * g5 + q;
        int tt = t > 17 ? 17 : t;      // dead lanes use a harmless valid addr
        int khkw = tt >> 1;
        int kh = khkw / 3;
        int kw = khkw - 3 * kh;
        Kbase[g5] = (kh * LCOLS + m + kw) * 2 + (tt & 1);
    }

    // ---- staging sweeps. body: lane -> (rr = lane>>4, grp j = lane&15),
    //      rows s0..s0+NR-1 (NR=4: all lanes; NR=2: lanes<32).
    //      halo: 2*NR tasks on lanes lane0.. (hr = h>>1, side = h&1). ----
    auto load_body = [&](int s0, int NR, float4* f4) {
        const int rr = lane >> 4;
        if (rr < NR) {
            const int gh = h0 - 1 + s0 + rr;
            const int j = lane & 15;
            if ((unsigned)gh < (unsigned)HH) {
                const float4* src = (const float4*)(x + (size_t)gh * WW + w0) + j;
                #pragma unroll
                for (int c = 0; c < CIN; ++c)
                    f4[c] = src[(size_t)c * (HWP / 4)];
            } else {
                #pragma unroll
                for (int c = 0; c < CIN; ++c)
                    f4[c] = make_float4(0.f, 0.f, 0.f, 0.f);
            }
        }
    };
    auto load_halo = [&](int s0, int NR, int lane0, float* f) {
        const int h = lane - lane0;
        if ((unsigned)h < (unsigned)(2 * NR)) {
            const int gh = h0 - 1 + s0 + (h >> 1);
            const int gw = (h & 1) ? (w0 + TW) : (w0 - 1);
            if ((unsigned)gh < (unsigned)HH && (unsigned)gw < (unsigned)WW) {
                const float* src = x + (size_t)gh * WW + gw;
                #pragma unroll
                for (int c = 0; c < CIN; ++c) f[c] = src[(size_t)c * HWP];
            } else {
                #pragma unroll
                for (int c = 0; c < CIN; ++c) f[c] = 0.f;
            }
        }
    };
    auto write_body = [&](int s0, int NR, const float4* f4) {
        const int rr = lane >> 4;
        if (rr < NR) {
            const int slot = s0 + rr;
            const int j = lane & 15;
            const int pbase = slot * LCOLS + 1 + 4 * j;   // first of 4 px
            #pragma unroll
            for (int k = 0; k < 4; ++k) {
                u32 pk[8];
                #pragma unroll
                for (int i = 0; i < 8; ++i) {
                    const float lo = ((const float*)&f4[2 * i])[k];
                    const float hi = ((const float*)&f4[2 * i + 1])[k];
                    pk[i] = cvt_pk_bf16(lo, hi);
                }
                #pragma unroll
                for (int half = 0; half < 2; ++half) {
                    const int cc = 2 * pbase + 2 * k + half;
                    *(uint4*)(sm + swz(cc) * 8) = *(uint4*)&pk[half * 4];
                }
            }
        }
    };
    auto write_halo = [&](int s0, int NR, int lane0, const float* f) {
        const int h = lane - lane0;
        if ((unsigned)h < (unsigned)(2 * NR)) {
            const int slot = s0 + (h >> 1);
            const int p = slot * LCOLS + ((h & 1) ? 65 : 0);
            u32 pk[8];
            #pragma unroll
            for (int i = 0; i < 8; ++i)
                pk[i] = cvt_pk_bf16(f[2 * i], f[2 * i + 1]);
            #pragma unroll
            for (int half = 0; half < 2; ++half) {
                const int cc = 2 * p + half;
                *(uint4*)(sm + swz(cc) * 8) = *(uint4*)&pk[half * 4];
            }
        }
    };

    // ---- compute 4 output rows r0..r0+3 (input slots r+kh, kh=0..2) ----
    auto compute4 = [&](int r0) {
        #pragma unroll
        for (int rr = 0; rr < 4; ++rr) {
            const int r = r0 + rr;
            #pragma unroll
            for (int g16 = 0; g16 < 4; ++g16) {
                v4f acc = {0.f, 0.f, 0.f, 0.f};
                #pragma unroll
                for (int g5 = 0; g5 < 5; ++g5) {
                    const int c = r * (LCOLS * 2) + g16 * 32 + Kbase[g5];
                    v8s b = *(const v8s*)(sm + swz(c) * 8);
                    acc = __builtin_amdgcn_mfma_f32_16x16x32_bf16(a[g5], b, acc, 0, 0, 0);
                }
                float* op = out + (size_t)(h0 + r) * WW + (w0 + g16 * 16 + m);
                #pragma unroll
                for (int i = 0; i < 4; ++i)
                    op[(size_t)(q * 4 + i) * HWP] = acc[i] + bl[i];
            }
        }
    };

    // ---- barrier-free pipeline (all vmcnt waits precede any stores) ----
    float4 fA[CIN];                 // sweep A rows -1..2; reused for C (7..8)
    float4 fB[CIN];                 // sweep B rows 3..6
    float hA[CIN], hB[CIN], hC[CIN];

    load_body(0, 4, fA);  load_halo(0, 4, 0, hA);   // issue A
    load_body(4, 4, fB);  load_halo(4, 4, 0, hB);   // issue B
    write_body(0, 4, fA); write_halo(0, 4, 0, hA);  // waits A only
    load_body(8, 2, fA);  load_halo(8, 2, 32, hC);  // issue C (reuse fA)
    write_body(4, 4, fB); write_halo(4, 4, 0, hB);  // waits B only
    write_body(8, 2, fA); write_halo(8, 2, 32, hC); // waits C only
    compute4(0);                                    // no vmem waits from here:
    compute4(4);                                    // stores free-flow to end
}

extern "C" void kernel_launch(void* const* d_in, const int* in_sizes, int n_in,
                              void* d_out, int out_size, void* d_ws, size_t ws_size,
                              hipStream_t stream) {
    const float* x = (const float*)d_in[0];
    const float* w = (const float*)d_in[1];
    const float* b = (const float*)d_in[2];
    float* out = (float*)d_out;
    dim3 grid(WW / TW, HH / TH);
    conv3x3_wave<<<grid, dim3(64), 0, stream>>>(x, w, b, out);
}